// Round 2
// baseline (1736.954 us; speedup 1.0000x reference)
//
#include <hip/hip_runtime.h>

// ---- problem constants ----
#define Bn 4
#define Nn 1024
#define Tn 12
#define Cn 256
#define Hn 8
#define DKn 32
#define Mrows 49152            // B*N*T
#define NEl 12582912LL         // B*N*T*C
#define SCALE_ 0.17677669529663687f  // 1/sqrt(32)

typedef __attribute__((ext_vector_type(4))) float f32x4;
typedef __attribute__((ext_vector_type(8))) short s16x8;

__device__ __forceinline__ ushort f2bfu(float x) {       // fp32 -> bf16 (RNE)
    unsigned u = __builtin_bit_cast(unsigned, x);
    u += 0x7fffu + ((u >> 16) & 1u);
    return (ushort)(u >> 16);
}
__device__ __forceinline__ float bfu2f(ushort h) {
    return __builtin_bit_cast(float, ((unsigned)h) << 16);
}
__device__ __forceinline__ void gl_lds16(const void* g, void* l) {
    __builtin_amdgcn_global_load_lds(
        (const __attribute__((address_space(1))) void*)g,
        (__attribute__((address_space(3))) void*)l, 16, 0, 0);
}

// ---------------- weight pre-conversion: fp32 -> bf16 hi + lo residual ----------------
struct WPtrs { const float* src[7]; };

__global__ __launch_bounds__(256)
void wconv_k(WPtrs w, ushort* __restrict__ Wh, ushort* __restrict__ Wl) {
    int idx = blockIdx.x * 256 + threadIdx.x;   // 7*65536 total, exact grid
    int which = idx >> 16, pos = idx & 65535;
    float x = w.src[which][pos];
    ushort h = f2bfu(x);
    Wh[idx] = h;
    Wl[idx] = f2bfu(x - bfu2f(h));
}

// ---------------- batched GEMM: Y[m,o] = sum_c A[m,c] * W[o,c] (+bias) ----------------
// 128x128 tile, BK=32, 256 threads = 4 waves in 2x2; global_load_lds staging for bf16
// sides with add-swizzled k-quads (2-way bank aliasing only). SPLIT = bf16x3 (~fp32).
struct GPtrs {
    const void*   A[4];
    const ushort* Wh[4];
    const ushort* Wl[4];
    void*         Y[4];
};

template<bool SPLIT, bool IN_BF16, bool OUT_BF16, bool BIAS>
__global__ __launch_bounds__(256)
void gemm_k(GPtrs p, const float* __restrict__ bias) {
    const int bt  = blockIdx.z;
    const int bm  = blockIdx.x * 128;
    const int bn  = blockIdx.y * 128;
    const int tid = threadIdx.x;
    const int lane = tid & 63;
    const int wave = tid >> 6;
    const int wr = (wave >> 1) * 64;
    const int wc = (wave & 1) * 64;

    constexpr int ASTR = IN_BF16 ? 32 : 40;   // linear for global_load_lds, padded for manual
    __shared__ __align__(16) short As[128 * ASTR];
    __shared__ __align__(16) short Bs[128 * 32];
    __shared__ __align__(16) short Al[SPLIT ? 128 * 40 : 8];
    __shared__ __align__(16) short Bl[SPLIT ? 128 * 32 : 8];

    f32x4 acc[4][4];
#pragma unroll
    for (int i = 0; i < 4; i++)
#pragma unroll
        for (int j = 0; j < 4; j++)
            acc[i][j] = (f32x4){0.f, 0.f, 0.f, 0.f};

    // staging indices
    const int ar_ = tid >> 1, ac_ = (tid & 1) * 16;          // fp32-A path: 16 elems/thread
    const int br_ = tid >> 2;                                // lds-load path: row within 64
    const int bgq = ((tid & 3) - (br_ >> 1)) & 3;            // global quad for swizzled slot

    const int am = lane & 15, kq = lane >> 4;

    for (int k0 = 0; k0 < 256; k0 += 32) {
        // ---- stage A ----
        if constexpr (IN_BF16) {
            const ushort* A = (const ushort*)p.A[bt];
            gl_lds16(A + (size_t)(bm + br_) * 256 + k0 + bgq * 8, &As[tid * 8]);
            gl_lds16(A + (size_t)(bm + 64 + br_) * 256 + k0 + bgq * 8, &As[2048 + tid * 8]);
        } else {
            const float* A = (const float*)p.A[bt];
            const float* g = A + (size_t)(bm + ar_) * 256 + k0 + ac_;
            f32x4 v0 = ((const f32x4*)g)[0];
            f32x4 v1 = ((const f32x4*)g)[1];
            f32x4 v2 = ((const f32x4*)g)[2];
            f32x4 v3 = ((const f32x4*)g)[3];
            s16x8 hi0, hi1, lo0, lo1;
#pragma unroll
            for (int j = 0; j < 8; j++) {
                float x0 = (j < 4) ? v0[j] : v1[j - 4];
                float x1 = (j < 4) ? v2[j] : v3[j - 4];
                ushort h0 = f2bfu(x0), h1 = f2bfu(x1);
                hi0[j] = (short)h0; hi1[j] = (short)h1;
                if constexpr (SPLIT) {
                    lo0[j] = (short)f2bfu(x0 - bfu2f(h0));
                    lo1[j] = (short)f2bfu(x1 - bfu2f(h1));
                }
            }
            *(s16x8*)&As[ar_ * 40 + ac_]     = hi0;
            *(s16x8*)&As[ar_ * 40 + ac_ + 8] = hi1;
            if constexpr (SPLIT) {
                *(s16x8*)&Al[ar_ * 40 + ac_]     = lo0;
                *(s16x8*)&Al[ar_ * 40 + ac_ + 8] = lo1;
            }
        }
        // ---- stage B (weights, bf16) via global_load_lds ----
        {
            const ushort* W = p.Wh[bt];
            gl_lds16(W + (size_t)(bn + br_) * 256 + k0 + bgq * 8, &Bs[tid * 8]);
            gl_lds16(W + (size_t)(bn + 64 + br_) * 256 + k0 + bgq * 8, &Bs[2048 + tid * 8]);
            if constexpr (SPLIT) {
                const ushort* Wlp = p.Wl[bt];
                gl_lds16(Wlp + (size_t)(bn + br_) * 256 + k0 + bgq * 8, &Bl[tid * 8]);
                gl_lds16(Wlp + (size_t)(bn + 64 + br_) * 256 + k0 + bgq * 8, &Bl[2048 + tid * 8]);
            }
        }
        __syncthreads();
        // ---- fragments + MFMA ----
        s16x8 a[4], alo[4];
#pragma unroll
        for (int mi = 0; mi < 4; mi++) {
            int row = wr + mi * 16 + am;
            if constexpr (IN_BF16) {
                a[mi] = *(const s16x8*)&As[row * 32 + ((kq + (row >> 1)) & 3) * 8];
            } else {
                a[mi] = *(const s16x8*)&As[row * 40 + kq * 8];
                if constexpr (SPLIT) alo[mi] = *(const s16x8*)&Al[row * 40 + kq * 8];
            }
        }
#pragma unroll
        for (int ni = 0; ni < 4; ni++) {
            int row = wc + ni * 16 + am;
            int ba  = row * 32 + ((kq + (row >> 1)) & 3) * 8;
            s16x8 b = *(const s16x8*)&Bs[ba];
            if constexpr (SPLIT) {
                s16x8 bl = *(const s16x8*)&Bl[ba];
#pragma unroll
                for (int mi = 0; mi < 4; mi++) {
                    acc[mi][ni] = __builtin_amdgcn_mfma_f32_16x16x32_bf16(a[mi],   b,  acc[mi][ni], 0, 0, 0);
                    acc[mi][ni] = __builtin_amdgcn_mfma_f32_16x16x32_bf16(alo[mi], b,  acc[mi][ni], 0, 0, 0);
                    acc[mi][ni] = __builtin_amdgcn_mfma_f32_16x16x32_bf16(a[mi],   bl, acc[mi][ni], 0, 0, 0);
                }
            } else {
#pragma unroll
                for (int mi = 0; mi < 4; mi++)
                    acc[mi][ni] = __builtin_amdgcn_mfma_f32_16x16x32_bf16(a[mi], b, acc[mi][ni], 0, 0, 0);
            }
        }
        __syncthreads();
    }
    // ---- epilogue: C/D layout col=lane&15, row=(lane>>4)*4+reg ----
#pragma unroll
    for (int mi = 0; mi < 4; mi++) {
#pragma unroll
        for (int ni = 0; ni < 4; ni++) {
            int col  = bn + wc + ni * 16 + am;
            int row0 = bm + wr + mi * 16 + kq * 4;
            float bv = BIAS ? bias[col] : 0.f;
#pragma unroll
            for (int rg = 0; rg < 4; rg++) {
                float v = acc[mi][ni][rg] + bv;
                size_t idx = (size_t)(row0 + rg) * 256 + col;
                if constexpr (OUT_BF16) ((ushort*)p.Y[bt])[idx] = f2bfu(v);
                else                    ((float*)p.Y[bt])[idx]  = v;
            }
        }
    }
}

// ---------------- attention: one wave per (b,n,h); register rows, broadcast LDS ----------------
#define PAD_ 36   // floats per row (16B-aligned, 2-way banks only)

__global__ __launch_bounds__(64)
void attn_k(const ushort* __restrict__ Qf, const float* __restrict__ Kf,
            const ushort* __restrict__ Vf, const float* __restrict__ Qs,
            const ushort* __restrict__ Ks, const ushort* __restrict__ Vs,
            const float* __restrict__ kj, const float* __restrict__ vf_fs,
            ushort* __restrict__ c0, ushort* __restrict__ c1,
            ushort* __restrict__ c2, ushort* __restrict__ c3)
{
    const int bn   = blockIdx.x;   // b*N + n
    const int h    = blockIdx.y;
    const int lane = threadIdx.x;

    __shared__ __align__(16) float sm[7 * 12 * PAD_];
    float* sQf = sm + 0 * 12 * PAD_;
    float* sKf = sm + 1 * 12 * PAD_;
    float* sKs = sm + 2 * 12 * PAD_;
    float* sQs = sm + 3 * 12 * PAD_;
    float* sqf = sm + 4 * 12 * PAD_;
    float* sVf = sm + 5 * 12 * PAD_;
    float* sVs = sm + 6 * 12 * PAD_;
    ushort* sOut = (ushort*)sm;    // aliases sQf/sKf (dead after scores), 3072B < 3456B

    const size_t base = (size_t)bn * (Tn * Cn) + (size_t)h * DKn;

    // ---- stage: fp32 tensors (float4) + bf16 tensors (ushort4->float4) ----
    for (int i = lane; i < 96; i += 64) {
        int t = i >> 3, dq = (i & 7) * 4;
        size_t g = base + (size_t)t * Cn + dq;
        *(f32x4*)&sKf[t * PAD_ + dq] = *(const f32x4*)&Kf[g];
        *(f32x4*)&sQs[t * PAD_ + dq] = *(const f32x4*)&Qs[g];
        ushort4 a0 = *(const ushort4*)&Qf[g];
        ushort4 a1 = *(const ushort4*)&Ks[g];
        ushort4 a2 = *(const ushort4*)&Vf[g];
        ushort4 a3 = *(const ushort4*)&Vs[g];
        *(f32x4*)&sQf[t * PAD_ + dq] = (f32x4){bfu2f(a0.x), bfu2f(a0.y), bfu2f(a0.z), bfu2f(a0.w)};
        *(f32x4*)&sKs[t * PAD_ + dq] = (f32x4){bfu2f(a1.x), bfu2f(a1.y), bfu2f(a1.z), bfu2f(a1.w)};
        *(f32x4*)&sVf[t * PAD_ + dq] = (f32x4){bfu2f(a2.x), bfu2f(a2.y), bfu2f(a2.z), bfu2f(a2.w)};
        *(f32x4*)&sVs[t * PAD_ + dq] = (f32x4){bfu2f(a3.x), bfu2f(a3.y), bfu2f(a3.z), bfu2f(a3.w)};
    }
    __syncthreads();
    // ---- FlowSpeed physics transform (fp32, matches reference) ----
    for (int i = lane; i < 384; i += 64) {
        int t = i >> 5, d = i & 31;
        float q = sQs[t * PAD_ + d];
        sqf[t * PAD_ + d] = kj[t] * (q - q * q / (vf_fs[t] + 1e-5f));
    }
    __syncthreads();

    // ---- per-lane: mat = lane>>4 (4 mats), t = lane&15 (12 active) ----
    const int mat = lane >> 4;
    const int t   = lane & 15;
    const int tc  = (t < 12) ? t : 11;
    const float *Arow, *Bmat, *Vmat;
    if (mat == 0)      { Arow = sQf; Bmat = sKf; Vmat = sVf; }   // z_ff
    else if (mat == 1) { Arow = sKf; Bmat = sqf; Vmat = sVf; }   // z_fs
    else if (mat == 2) { Arow = sKs; Bmat = sQf; Vmat = sVs; }   // z_sf
    else               { Arow = sQs; Bmat = sKs; Vmat = sVs; }   // z_ss

    f32x4 ar[8];
#pragma unroll
    for (int j = 0; j < 8; j++) ar[j] = *(const f32x4*)&Arow[tc * PAD_ + j * 4];

    float sc[12];
#pragma unroll
    for (int s = 0; s < 12; s++) {
        f32x4 acc = (f32x4){0.f, 0.f, 0.f, 0.f};
#pragma unroll
        for (int j = 0; j < 8; j++) acc += ar[j] * *(const f32x4*)&Bmat[s * PAD_ + j * 4];
        sc[s] = (acc[0] + acc[1] + acc[2] + acc[3]) * SCALE_;
    }
    // ---- softmax (in-register) ----
    float mx = sc[0];
#pragma unroll
    for (int s = 1; s < 12; s++) mx = fmaxf(mx, sc[s]);
    float sum = 0.f;
#pragma unroll
    for (int s = 0; s < 12; s++) { sc[s] = __expf(sc[s] - mx); sum += sc[s]; }
    float inv = 1.f / sum;
    // ---- ctx (V rows broadcast) ----
    f32x4 o[8];
#pragma unroll
    for (int j = 0; j < 8; j++) o[j] = (f32x4){0.f, 0.f, 0.f, 0.f};
#pragma unroll
    for (int s = 0; s < 12; s++) {
        float w = sc[s] * inv;
#pragma unroll
        for (int j = 0; j < 8; j++) o[j] += w * *(const f32x4*)&Vmat[s * PAD_ + j * 4];
    }
    __syncthreads();   // sQf/sKf dead; safe to alias sOut
    if (t < 12) {
#pragma unroll
        for (int j = 0; j < 8; j++) {
            ushort4 u = {f2bfu(o[j][0]), f2bfu(o[j][1]), f2bfu(o[j][2]), f2bfu(o[j][3])};
            *(ushort4*)&sOut[mat * 384 + t * 32 + j * 4] = u;
        }
    }
    __syncthreads();
    // ---- coalesced bf16 store ----
    ushort* dsts[4] = {c0, c1, c2, c3};
#pragma unroll
    for (int m = 0; m < 4; m++) {
        for (int i = lane; i < 96; i += 64) {
            int tt = i >> 3, dq = (i & 7) * 4;
            *(ushort4*)&dsts[m][base + (size_t)tt * Cn + dq] =
                *(const ushort4*)&sOut[m * 384 + tt * 32 + dq];
        }
    }
}

// ---------------- host launcher ----------------
extern "C" void kernel_launch(void* const* d_in, const int* in_sizes, int n_in,
                              void* d_out, int out_size, void* d_ws, size_t ws_size,
                              hipStream_t stream) {
    (void)in_sizes; (void)n_in; (void)out_size; (void)ws_size;

    const float* flow_q  = (const float*)d_in[0];
    const float* flow_k  = (const float*)d_in[1];
    const float* flow_v  = (const float*)d_in[2];
    const float* speed_q = (const float*)d_in[3];
    const float* speed_k = (const float*)d_in[4];
    const float* speed_v = (const float*)d_in[5];
    const float* w_fq  = (const float*)d_in[6];
    const float* w_fk  = (const float*)d_in[7];
    const float* w_fv  = (const float*)d_in[8];
    const float* w_sq  = (const float*)d_in[9];
    const float* w_sk  = (const float*)d_in[10];
    const float* w_sv  = (const float*)d_in[11];
    const float* w_out = (const float*)d_in[12];
    const float* b_out = (const float*)d_in[13];
    const float* kj    = (const float*)d_in[14];
    const float* vf    = (const float*)d_in[15];

    char* ws = (char*)d_ws;
    size_t off = 0;
    auto alloc = [&](size_t bytes) -> void* {
        void* p = ws + off;
        off += (bytes + 255) & ~(size_t)255;
        return p;
    };
    ushort* Wh = (ushort*)alloc(7 * 65536 * 2);
    ushort* Wl = (ushort*)alloc(7 * 65536 * 2);
    ushort* Qf = (ushort*)alloc(NEl * 2);
    float*  Kf = (float*) alloc(NEl * 4);   // fp32: sensitive (z_fs logits)
    ushort* Vf = (ushort*)alloc(NEl * 2);
    float*  Qs = (float*) alloc(NEl * 4);   // fp32: feeds physics transform
    ushort* Ks = (ushort*)alloc(NEl * 2);
    ushort* Vs = (ushort*)alloc(NEl * 2);
    ushort* c0 = (ushort*)alloc(NEl * 2);
    ushort* c1 = (ushort*)alloc(NEl * 2);
    ushort* c2 = (ushort*)alloc(NEl * 2);
    ushort* c3 = (ushort*)alloc(NEl * 2);

    float* out = (float*)d_out;

    WPtrs wp;
    wp.src[0] = w_fq; wp.src[1] = w_fk; wp.src[2] = w_fv; wp.src[3] = w_sq;
    wp.src[4] = w_sk; wp.src[5] = w_sv; wp.src[6] = w_out;
    wconv_k<<<dim3(7 * 65536 / 256), 256, 0, stream>>>(wp, Wh, Wl);

    // 1a) insensitive projections: 1-pass bf16, bf16 out
    GPtrs p1;
    p1.A[0] = flow_q;  p1.Wh[0] = Wh + 0 * 65536; p1.Wl[0] = Wl + 0 * 65536; p1.Y[0] = Qf;
    p1.A[1] = flow_v;  p1.Wh[1] = Wh + 2 * 65536; p1.Wl[1] = Wl + 2 * 65536; p1.Y[1] = Vf;
    p1.A[2] = speed_k; p1.Wh[2] = Wh + 4 * 65536; p1.Wl[2] = Wl + 4 * 65536; p1.Y[2] = Ks;
    p1.A[3] = speed_v; p1.Wh[3] = Wh + 5 * 65536; p1.Wl[3] = Wl + 5 * 65536; p1.Y[3] = Vs;
    gemm_k<false, false, true, false><<<dim3(Mrows / 128, 2, 4), 256, 0, stream>>>(p1, nullptr);

    // 1b) sensitive projections: split bf16x3 (~fp32), fp32 out
    GPtrs p2;
    p2.A[0] = flow_k;  p2.Wh[0] = Wh + 1 * 65536; p2.Wl[0] = Wl + 1 * 65536; p2.Y[0] = Kf;
    p2.A[1] = speed_q; p2.Wh[1] = Wh + 3 * 65536; p2.Wl[1] = Wl + 3 * 65536; p2.Y[1] = Qs;
    p2.A[2] = flow_k;  p2.Wh[2] = Wh + 1 * 65536; p2.Wl[2] = Wl + 1 * 65536; p2.Y[2] = Kf;
    p2.A[3] = flow_k;  p2.Wh[3] = Wh + 1 * 65536; p2.Wl[3] = Wl + 1 * 65536; p2.Y[3] = Kf;
    gemm_k<true, false, false, false><<<dim3(Mrows / 128, 2, 2), 256, 0, stream>>>(p2, nullptr);

    // 2) attention (fp32), writes bf16 ctx
    attn_k<<<dim3(Bn * Nn, Hn), 64, 0, stream>>>(Qf, Kf, Vf, Qs, Ks, Vs, kj, vf, c0, c1, c2, c3);

    // 3) out projections: bf16 in, fp32 out + bias
    GPtrs p3;
    p3.A[0] = c0; p3.Wh[0] = Wh + 6 * 65536; p3.Wl[0] = Wl + 6 * 65536; p3.Y[0] = out;
    p3.A[1] = c1; p3.Wh[1] = Wh + 6 * 65536; p3.Wl[1] = Wl + 6 * 65536; p3.Y[1] = out + NEl;
    p3.A[2] = c2; p3.Wh[2] = Wh + 6 * 65536; p3.Wl[2] = Wl + 6 * 65536; p3.Y[2] = out + 2 * NEl;
    p3.A[3] = c3; p3.Wh[3] = Wh + 6 * 65536; p3.Wl[3] = Wl + 6 * 65536; p3.Y[3] = out + 3 * NEl;
    gemm_k<false, true, false, true><<<dim3(Mrows / 128, 2, 4), 256, 0, stream>>>(p3, b_out);
}